// Round 1
// baseline (361.920 us; speedup 1.0000x reference)
//
#include <hip/hip_runtime.h>

typedef unsigned short ushort_t;
typedef __attribute__((ext_vector_type(8))) short s16x8;   // 8 bf16 (4 VGPRs) MFMA A/B frag
typedef __attribute__((ext_vector_type(4))) float f32x4;   // 4 f32 MFMA C/D frag

#define B_PATHS 8192
#define NSTEP   30
#define DD      100
#define HH      110
#define TT      29            // number of subnets
#define ROWSTR  3000          // NSTEP*DD floats per path
#define LDK     136           // padded k-stride (bf16 elems): 272B rows -> 2-way (free) LDS banking
#define NROWS   112           // W rows staged in LDS (n up to 112; tiles 0..6)
#define WMATSZ  (128*LDK)     // prep layout: 128 rows per matrix (ushort elems)
#define DT_C    (1.0f/30.0f)
#define R_C     0.05f
#define EPS_C   1e-3f

__device__ __forceinline__ ushort_t f2bf(float f) {  // RNE f32->bf16
  unsigned u = __float_as_uint(f);
  u = u + 0x7FFFu + ((u >> 16) & 1u);
  return (ushort_t)(u >> 16);
}

// ---------------------------------------------------------------------------
// Prep: fold BN into weights/biases, transpose to [n][k] bf16 padded 128x136.
//   W1' [k<100][n<110] = s0[k]*W1 ;               c1[n] = sum_k h0[k] W1[k][n]
//   W2' [k<110][n<110] = s1[k]*W2 ;               c2[n] = sum_k h1[k] W2[k][n]
//   W3''[k<110][n<100] = s2[k]*W3*s3[n] ;         c3[n] = (sum_k h2[k] W3[k][n])*s3[n] + h3[n]
// ---------------------------------------------------------------------------
__global__ void prep_kernel(const float* __restrict__ W1, const float* __restrict__ W2,
                            const float* __restrict__ W3,
                            const float* g0, const float* b0, const float* m0, const float* v0,
                            const float* g1, const float* b1, const float* m1, const float* v1,
                            const float* g2, const float* b2, const float* m2, const float* v2,
                            const float* g3, const float* b3, const float* m3, const float* v3,
                            ushort_t* __restrict__ wprep, float* __restrict__ bprep)
{
  const int mat = blockIdx.x, t = blockIdx.y, tid = threadIdx.x;
  __shared__ float wsh[110*110];
  __shared__ float sin_[112], hin_[112], sout_[112], hout_[112];

  int Kr, Nr; const float* W; const float *g, *bb, *mm, *vv;
  if (mat == 0)      { Kr = 100; Nr = 110; W = W1 + t*11000; g = g0+t*100; bb = b0+t*100; mm = m0+t*100; vv = v0+t*100; }
  else if (mat == 1) { Kr = 110; Nr = 110; W = W2 + t*12100; g = g1+t*110; bb = b1+t*110; mm = m1+t*110; vv = v1+t*110; }
  else               { Kr = 110; Nr = 100; W = W3 + t*11000; g = g2+t*110; bb = b2+t*110; mm = m2+t*110; vv = v2+t*110; }

  if (tid < Kr) {
    float s = g[tid] * rsqrtf(vv[tid] + EPS_C);
    sin_[tid] = s; hin_[tid] = bb[tid] - mm[tid]*s;
  }
  if (mat == 2 && tid < Nr) {
    float s = g3[t*100+tid] * rsqrtf(v3[t*100+tid] + EPS_C);
    sout_[tid] = s; hout_[tid] = b3[t*100+tid] - m3[t*100+tid]*s;
  }
  for (int i = tid; i < Kr*Nr; i += 256) wsh[i] = W[i];
  __syncthreads();

  if (tid < 128) {
    float c = 0.f;
    if (tid < Nr) {
      for (int k = 0; k < Kr; ++k) c += hin_[k] * wsh[k*Nr + tid];
      if (mat == 2) c = c * sout_[tid] + hout_[tid];
    }
    bprep[(t*3 + mat)*128 + tid] = c;
  }
  ushort_t* wo = wprep + (size_t)(t*3 + mat) * WMATSZ;
  for (int idx = tid; idx < 128*LDK; idx += 256) {
    int n = idx / LDK, k = idx - n*LDK;
    float v = 0.f;
    if (n < Nr && k < Kr) {
      v = sin_[k] * wsh[k*Nr + n];
      if (mat == 2) v *= sout_[n];
    }
    wo[idx] = f2bf(v);
  }
}

// ---------------------------------------------------------------------------
// Fused subnet: per block = (t, 64-row tile). 3x MFMA GEMM + relu, epilogue
// computes s_{t+1}[b] = sum_d sigma_d * X[b,xt,d] * Z_t[b,d] * DW[b,t+1,d].
// ---------------------------------------------------------------------------
__device__ __forceinline__ void gemm_relu_stage(const ushort_t* actIn, const ushort_t* wb,
                                                const float* __restrict__ biasg,
                                                ushort_t* actOut, int wr, int lrow, int quad)
{
  f32x4 acc[7];
  const f32x4 z4 = {0.f, 0.f, 0.f, 0.f};
#pragma unroll
  for (int nt = 0; nt < 7; ++nt) acc[nt] = z4;
#pragma unroll
  for (int kb = 0; kb < 4; ++kb) {
    s16x8 a = *(const s16x8*)(actIn + (wr + lrow)*LDK + kb*32 + quad*8);
#pragma unroll
    for (int nt = 0; nt < 7; ++nt) {
      s16x8 b = *(const s16x8*)(wb + (nt*16 + lrow)*LDK + kb*32 + quad*8);
      acc[nt] = __builtin_amdgcn_mfma_f32_16x16x32_bf16(a, b, acc[nt], 0, 0, 0);
    }
  }
#pragma unroll
  for (int nt = 0; nt < 7; ++nt) {
    const int col = nt*16 + lrow;
    const float bv = biasg[col];
#pragma unroll
    for (int r = 0; r < 4; ++r) {
      float u = acc[nt][r] + bv;            // C/D layout: row=quad*4+r, col=lane&15
      u = u > 0.f ? u : 0.f;
      actOut[(wr + quad*4 + r)*LDK + col] = f2bf(u);
    }
  }
}

__global__ __launch_bounds__(256, 2)
void subnet_kernel(const float* __restrict__ X, const float* __restrict__ DW,
                   const float* __restrict__ sigmas,
                   const ushort_t* __restrict__ wprep, const float* __restrict__ bprep,
                   float* __restrict__ sbuf)
{
  __shared__ __align__(16) ushort_t actA[64*LDK];     // 17408 B
  __shared__ __align__(16) ushort_t actB[64*LDK];     // 17408 B
  __shared__ __align__(16) ushort_t wbuf[NROWS*LDK];  // 30464 B  (total 65280 <= 64 KiB)

  const int tid  = threadIdx.x;
  const int t    = blockIdx.y;
  const int m0   = blockIdx.x * 64;
  const int lane = tid & 63, lrow = lane & 15, quad = lane >> 4;
  const int wr   = (tid >> 6) * 16;   // wave's 16-row slice

  // zero act buffers (pads must be 0 for the K=128 MFMA sweep)
  {
    const uint4 z4 = {0u, 0u, 0u, 0u};
    uint4* pA = (uint4*)actA; uint4* pB = (uint4*)actB;
    for (int i = tid; i < 1088; i += 256) { pA[i] = z4; pB[i] = z4; }
  }
  __syncthreads();

  // load X[:, t+1, :] tile -> bf16 actA, and stage W1'
  for (int j = tid; j < 64*25; j += 256) {
    int r = j / 25, c = j - r*25;
    const float4 v = *(const float4*)(X + (size_t)(m0 + r)*ROWSTR + (t+1)*DD + c*4);
    ushort4 u; u.x = f2bf(v.x); u.y = f2bf(v.y); u.z = f2bf(v.z); u.w = f2bf(v.w);
    *(ushort4*)(actA + r*LDK + c*4) = u;
  }
  {
    const uint4* ws = (const uint4*)(wprep + (size_t)(t*3 + 0)*WMATSZ);
    uint4* wd = (uint4*)wbuf;
    for (int j = tid; j < (NROWS*LDK)/8; j += 256) wd[j] = ws[j];
  }
  __syncthreads();

  gemm_relu_stage(actA, wbuf, bprep + (t*3 + 0)*128, actB, wr, lrow, quad);
  __syncthreads();
  {
    const uint4* ws = (const uint4*)(wprep + (size_t)(t*3 + 1)*WMATSZ);
    uint4* wd = (uint4*)wbuf;
    for (int j = tid; j < (NROWS*LDK)/8; j += 256) wd[j] = ws[j];
  }
  __syncthreads();

  gemm_relu_stage(actB, wbuf, bprep + (t*3 + 1)*128, actA, wr, lrow, quad);
  __syncthreads();
  {
    const uint4* ws = (const uint4*)(wprep + (size_t)(t*3 + 2)*WMATSZ);
    uint4* wd = (uint4*)wbuf;
    for (int j = tid; j < (NROWS*LDK)/8; j += 256) wd[j] = ws[j];
  }
  __syncthreads();

  // GEMM3 + fused s epilogue (Z never materialized)
  {
    f32x4 acc[7];
    const f32x4 z4 = {0.f, 0.f, 0.f, 0.f};
#pragma unroll
    for (int nt = 0; nt < 7; ++nt) acc[nt] = z4;
#pragma unroll
    for (int kb = 0; kb < 4; ++kb) {
      s16x8 a = *(const s16x8*)(actA + (wr + lrow)*LDK + kb*32 + quad*8);
#pragma unroll
      for (int nt = 0; nt < 7; ++nt) {
        s16x8 b = *(const s16x8*)(wbuf + (nt*16 + lrow)*LDK + kb*32 + quad*8);
        acc[nt] = __builtin_amdgcn_mfma_f32_16x16x32_bf16(a, b, acc[nt], 0, 0, 0);
      }
    }
    const float* biasg = bprep + (t*3 + 2)*128;
    const int xt = (t == TT - 1) ? (NSTEP - 2) : (t + 1);  // final step uses X[:,-2,:]
    float p[4] = {0.f, 0.f, 0.f, 0.f};
#pragma unroll
    for (int nt = 0; nt < 7; ++nt) {
      const int d = nt*16 + lrow;
      if (d < DD) {
        const float sg = sigmas[d];
        const float bv = biasg[d];
#pragma unroll
        for (int r = 0; r < 4; ++r) {
          const int b = m0 + wr + quad*4 + r;
          const float xv = X[(size_t)b*ROWSTR + xt*DD + d];
          const float dv = DW[(size_t)b*ROWSTR + (t+1)*DD + d];
          const float zv = acc[nt][r] + bv;     // bn3 already folded
          p[r] = fmaf(sg*xv*dv, zv, p[r]);
        }
      }
    }
#pragma unroll
    for (int off = 1; off < 16; off <<= 1) {
#pragma unroll
      for (int r = 0; r < 4; ++r) p[r] += __shfl_xor(p[r], off, 64);
    }
    if (lrow == 0) {
      float4 o; o.x = p[0]; o.y = p[1]; o.z = p[2]; o.w = p[3];
      *(float4*)(sbuf + (size_t)(t+1)*B_PATHS + m0 + wr + quad*4) = o;
    }
  }
}

// ---------------------------------------------------------------------------
// Y recursion: y = y + R*y*DT + s_tau, tau = 0..29 ; s_0 uses z_init.
// ---------------------------------------------------------------------------
__global__ void y_kernel(const float* __restrict__ X, const float* __restrict__ DW,
                         const float* __restrict__ sigmas, const float* __restrict__ y_init,
                         const float* __restrict__ z_init, const float* __restrict__ sbuf,
                         float* __restrict__ out)
{
  const int b = blockIdx.x * blockDim.x + threadIdx.x;
  const float* xr = X + (size_t)b * ROWSTR;   // step 0
  const float* dr = DW + (size_t)b * ROWSTR;
  float s0 = 0.f;
#pragma unroll 5
  for (int c = 0; c < 25; ++c) {
    float4 xv = *(const float4*)(xr + c*4);
    float4 dv = *(const float4*)(dr + c*4);
    float4 sg = *(const float4*)(sigmas + c*4);
    float4 zv = *(const float4*)(z_init + c*4);
    s0 += sg.x*xv.x*zv.x*dv.x;
    s0 += sg.y*xv.y*zv.y*dv.y;
    s0 += sg.z*xv.z*zv.z*dv.z;
    s0 += sg.w*xv.w*zv.w*dv.w;
  }
  float y = y_init[0];
  y = y + R_C*y*DT_C + s0;
  for (int tau = 1; tau < NSTEP; ++tau)
    y = y + R_C*y*DT_C + sbuf[(size_t)tau*B_PATHS + b];
  out[b] = y;
}

extern "C" void kernel_launch(void* const* d_in, const int* in_sizes, int n_in,
                              void* d_out, int out_size, void* d_ws, size_t ws_size,
                              hipStream_t stream) {
  const float* X      = (const float*)d_in[0];
  const float* DWs    = (const float*)d_in[1];
  const float* sigmas = (const float*)d_in[2];
  const float* y_init = (const float*)d_in[3];
  const float* z_init = (const float*)d_in[4];
  const float* W1     = (const float*)d_in[5];
  const float* W2     = (const float*)d_in[6];
  const float* W3     = (const float*)d_in[7];
  const float* bn[16];
  for (int i = 0; i < 16; ++i) bn[i] = (const float*)d_in[8 + i];

  char* ws = (char*)d_ws;
  ushort_t* wprep = (ushort_t*)ws;                     // 29*3*128*136*2 = 3,028,992 B
  float*    bprep = (float*)(ws + 3028992);            // 29*3*128*4     =    44,544 B
  float*    sbuf  = (float*)(ws + 3073536);            // 30*8192*4      =   983,040 B
  float*    out   = (float*)d_out;

  prep_kernel<<<dim3(3, TT), 256, 0, stream>>>(
      W1, W2, W3,
      bn[0], bn[1], bn[2], bn[3],  bn[4], bn[5], bn[6], bn[7],
      bn[8], bn[9], bn[10], bn[11], bn[12], bn[13], bn[14], bn[15],
      wprep, bprep);
  subnet_kernel<<<dim3(B_PATHS/64, TT), 256, 0, stream>>>(
      X, DWs, sigmas, wprep, bprep, sbuf);
  y_kernel<<<dim3(B_PATHS/256), 256, 0, stream>>>(
      X, DWs, sigmas, y_init, z_init, sbuf, out);
}

// Round 2
// 335.784 us; speedup vs baseline: 1.0778x; 1.0778x over previous
//
#include <hip/hip_runtime.h>

typedef unsigned short ushort_t;
typedef __attribute__((ext_vector_type(8))) short s16x8;   // 8 bf16 (4 VGPRs) MFMA A/B frag
typedef __attribute__((ext_vector_type(4))) float f32x4;   // 4 f32 MFMA C/D frag

#define B_PATHS 8192
#define NSTEP   30
#define DD      100
#define HH      110
#define TT      29            // number of subnets
#define ROWSTR  3000          // NSTEP*DD floats per path
#define LDK     136           // padded k-stride (bf16 elems) for act tiles; 272B rows
#define WFRAGSZ 14336         // per-stage frag-ordered W: 4 kb * 7 nt * 64 lanes * 8 elems
#define DT_C    (1.0f/30.0f)
#define R_C     0.05f
#define EPS_C   1e-3f

__device__ __forceinline__ ushort_t f2bf(float f) {  // RNE f32->bf16
  unsigned u = __float_as_uint(f);
  u = u + 0x7FFFu + ((u >> 16) & 1u);
  return (ushort_t)(u >> 16);
}
__device__ __forceinline__ float bf2f(ushort_t u) {
  return __uint_as_float(((unsigned)u) << 16);
}

// ---------------------------------------------------------------------------
// Prep: fold BN into weights/biases; emit W in MFMA B-fragment order:
//   elem j of chunk c=((kb*7+nt)*64+lane):  B[n=nt*16+(lane&15)][k=kb*32+(lane>>4)*8+j]
// so the subnet kernel loads B-frags straight from global (L2) with dwordx4.
// ---------------------------------------------------------------------------
__global__ void prep_kernel(const float* __restrict__ W1, const float* __restrict__ W2,
                            const float* __restrict__ W3,
                            const float* g0, const float* b0, const float* m0, const float* v0,
                            const float* g1, const float* b1, const float* m1, const float* v1,
                            const float* g2, const float* b2, const float* m2, const float* v2,
                            const float* g3, const float* b3, const float* m3, const float* v3,
                            ushort_t* __restrict__ wprep, float* __restrict__ bprep)
{
  const int mat = blockIdx.x, t = blockIdx.y, tid = threadIdx.x;
  __shared__ float wsh[110*110];
  __shared__ float sin_[112], hin_[112], sout_[112], hout_[112];

  int Kr, Nr; const float* W; const float *g, *bb, *mm, *vv;
  if (mat == 0)      { Kr = 100; Nr = 110; W = W1 + t*11000; g = g0+t*100; bb = b0+t*100; mm = m0+t*100; vv = v0+t*100; }
  else if (mat == 1) { Kr = 110; Nr = 110; W = W2 + t*12100; g = g1+t*110; bb = b1+t*110; mm = m1+t*110; vv = v1+t*110; }
  else               { Kr = 110; Nr = 100; W = W3 + t*11000; g = g2+t*110; bb = b2+t*110; mm = m2+t*110; vv = v2+t*110; }

  if (tid < Kr) {
    float s = g[tid] * rsqrtf(vv[tid] + EPS_C);
    sin_[tid] = s; hin_[tid] = bb[tid] - mm[tid]*s;
  }
  if (mat == 2 && tid < Nr) {
    float s = g3[t*100+tid] * rsqrtf(v3[t*100+tid] + EPS_C);
    sout_[tid] = s; hout_[tid] = b3[t*100+tid] - m3[t*100+tid]*s;
  }
  for (int i = tid; i < Kr*Nr; i += 256) wsh[i] = W[i];
  __syncthreads();

  if (tid < 128) {
    float c = 0.f;
    if (tid < Nr) {
      for (int k = 0; k < Kr; ++k) c += hin_[k] * wsh[k*Nr + tid];
      if (mat == 2) c = c * sout_[tid] + hout_[tid];
    }
    bprep[(t*3 + mat)*128 + tid] = c;
  }

  ushort_t* wo = wprep + (size_t)(t*3 + mat) * WFRAGSZ;
  for (int ch = tid; ch < 1792; ch += 256) {            // 1792 chunks of 8 elems
    const int lane = ch & 63, ntkb = ch >> 6;
    const int nt = ntkb % 7, kb = ntkb / 7;
    const int n  = nt*16 + (lane & 15);
    const int k0 = kb*32 + (lane >> 4)*8;
    ushort_t tmp[8];
#pragma unroll
    for (int j = 0; j < 8; ++j) {
      const int k = k0 + j;
      float v = 0.f;
      if (n < Nr && k < Kr) {
        v = sin_[k] * wsh[k*Nr + n];
        if (mat == 2) v *= sout_[n];
      }
      tmp[j] = f2bf(v);
    }
    ushort4 lo; lo.x = tmp[0]; lo.y = tmp[1]; lo.z = tmp[2]; lo.w = tmp[3];
    ushort4 hi; hi.x = tmp[4]; hi.y = tmp[5]; hi.z = tmp[6]; hi.w = tmp[7];
    *(ushort4*)(wo + ch*8)     = lo;
    *(ushort4*)(wo + ch*8 + 4) = hi;
  }
}

// ---------------------------------------------------------------------------
// One MLP stage: A from LDS, B-frags straight from global (L2-resident,
// frag-ordered => global_load_dwordx4, perfectly coalesced). Out -> LDS bf16.
// ---------------------------------------------------------------------------
__device__ __forceinline__ void mlp_stage(const ushort_t* actIn, const ushort_t* __restrict__ wfrag,
                                          const float* __restrict__ biasg, ushort_t* actOut,
                                          int wr, int lane, int lrow, int quad, bool relu)
{
  f32x4 acc[7];
  const f32x4 z4 = {0.f, 0.f, 0.f, 0.f};
#pragma unroll
  for (int nt = 0; nt < 7; ++nt) acc[nt] = z4;
  s16x8 a[4];
#pragma unroll
  for (int kb = 0; kb < 4; ++kb)
    a[kb] = *(const s16x8*)(actIn + (wr + lrow)*LDK + kb*32 + quad*8);
#pragma unroll
  for (int kb = 0; kb < 4; ++kb) {
#pragma unroll
    for (int nt = 0; nt < 7; ++nt) {
      s16x8 b = *(const s16x8*)(wfrag + ((kb*7 + nt)*64 + lane)*8);
      acc[nt] = __builtin_amdgcn_mfma_f32_16x16x32_bf16(a[kb], b, acc[nt], 0, 0, 0);
    }
  }
#pragma unroll
  for (int nt = 0; nt < 7; ++nt) {
    const int col = nt*16 + lrow;
    const float bv = biasg[col];
#pragma unroll
    for (int r = 0; r < 4; ++r) {
      float u = acc[nt][r] + bv;            // C/D layout: row=quad*4+r, col=lane&15
      if (relu) u = u > 0.f ? u : 0.f;
      actOut[(wr + quad*4 + r)*LDK + col] = f2bf(u);
    }
  }
  // maintain zero pad cols [112,128) so next stage's K-sweep reads zeros
#pragma unroll
  for (int r = 0; r < 4; ++r)
    actOut[(wr + quad*4 + r)*LDK + 112 + lrow] = 0;
}

// ---------------------------------------------------------------------------
// Fused subnet: block = (t, 64-row tile). 3 MFMA stages + fused s epilogue.
// ---------------------------------------------------------------------------
__global__ __launch_bounds__(256, 4)
void subnet_kernel(const float* __restrict__ X, const float* __restrict__ DW,
                   const float* __restrict__ sigmas,
                   const ushort_t* __restrict__ wprep, const float* __restrict__ bprep,
                   float* __restrict__ sbuf)
{
  __shared__ __align__(16) ushort_t actA[64*LDK];     // 17408 B
  __shared__ __align__(16) ushort_t actB[64*LDK];     // 17408 B   (total 34816)

  const int tid  = threadIdx.x;
  const int t    = blockIdx.y;
  const int m0   = blockIdx.x * 64;
  const int lane = tid & 63, lrow = lane & 15, quad = lane >> 4;
  const int wr   = (tid >> 6) * 16;   // wave's 16-row slice

  // stage X[:, t+1, :] tile -> bf16 actA (cols 100..127 zero-filled inline)
  for (int j = tid; j < 64*32; j += 256) {
    const int r = j >> 5, c = j & 31;          // c indexes float4 groups (128 cols)
    ushort4 u; u.x = 0; u.y = 0; u.z = 0; u.w = 0;
    if (c < 25) {
      const float4 v = *(const float4*)(X + (size_t)(m0 + r)*ROWSTR + (t+1)*DD + c*4);
      u.x = f2bf(v.x); u.y = f2bf(v.y); u.z = f2bf(v.z); u.w = f2bf(v.w);
    }
    *(ushort4*)(actA + r*LDK + c*4) = u;
  }
  __syncthreads();

  const ushort_t* wf = wprep + (size_t)(t*3) * WFRAGSZ;
  const float*    bg = bprep + (t*3) * 128;

  mlp_stage(actA, wf,             bg,       actB, wr, lane, lrow, quad, true);
  __syncthreads();
  mlp_stage(actB, wf + WFRAGSZ,   bg + 128, actA, wr, lane, lrow, quad, true);
  __syncthreads();
  mlp_stage(actA, wf + 2*WFRAGSZ, bg + 256, actB, wr, lane, lrow, quad, false); // Z (bn3 folded)
  __syncthreads();

  // epilogue: s[b] = sum_d sigma_d * X[b,xt,d] * Z[b,d] * DW[b,t+1,d]
  // 4 threads per row, float4 loads (X/DW rows are L1/L2-hot from staging)
  {
    const int row = tid >> 2, part = tid & 3;
    const int b   = m0 + row;
    const int xt  = (t == TT - 1) ? (NSTEP - 2) : (t + 1);
    const float* xr = X  + (size_t)b*ROWSTR + xt*DD;
    const float* dr = DW + (size_t)b*ROWSTR + (t+1)*DD;
    float p = 0.f;
#pragma unroll
    for (int g = part; g < 25; g += 4) {
      const float4 xv = *(const float4*)(xr + g*4);
      const float4 dv = *(const float4*)(dr + g*4);
      const float4 sg = *(const float4*)(sigmas + g*4);
      const ushort4 zu = *(const ushort4*)(actB + row*LDK + g*4);
      p += sg.x*xv.x*dv.x*bf2f(zu.x);
      p += sg.y*xv.y*dv.y*bf2f(zu.y);
      p += sg.z*xv.z*dv.z*bf2f(zu.z);
      p += sg.w*xv.w*dv.w*bf2f(zu.w);
    }
    p += __shfl_xor(p, 1, 64);
    p += __shfl_xor(p, 2, 64);
    if (part == 0)
      sbuf[(size_t)(t+1)*B_PATHS + b] = p;
  }
}

// ---------------------------------------------------------------------------
// Y recursion: y = y + R*y*DT + s_tau, tau = 0..29 ; s_0 uses z_init.
// ---------------------------------------------------------------------------
__global__ void y_kernel(const float* __restrict__ X, const float* __restrict__ DW,
                         const float* __restrict__ sigmas, const float* __restrict__ y_init,
                         const float* __restrict__ z_init, const float* __restrict__ sbuf,
                         float* __restrict__ out)
{
  const int b = blockIdx.x * blockDim.x + threadIdx.x;
  const float* xr = X + (size_t)b * ROWSTR;   // step 0
  const float* dr = DW + (size_t)b * ROWSTR;
  float s0 = 0.f;
#pragma unroll 5
  for (int c = 0; c < 25; ++c) {
    float4 xv = *(const float4*)(xr + c*4);
    float4 dv = *(const float4*)(dr + c*4);
    float4 sg = *(const float4*)(sigmas + c*4);
    float4 zv = *(const float4*)(z_init + c*4);
    s0 += sg.x*xv.x*zv.x*dv.x;
    s0 += sg.y*xv.y*zv.y*dv.y;
    s0 += sg.z*xv.z*zv.z*dv.z;
    s0 += sg.w*xv.w*zv.w*dv.w;
  }
  float y = y_init[0];
  y = y + R_C*y*DT_C + s0;
#pragma unroll
  for (int tau = 1; tau < NSTEP; ++tau)
    y = y + R_C*y*DT_C + sbuf[(size_t)tau*B_PATHS + b];
  out[b] = y;
}

extern "C" void kernel_launch(void* const* d_in, const int* in_sizes, int n_in,
                              void* d_out, int out_size, void* d_ws, size_t ws_size,
                              hipStream_t stream) {
  const float* X      = (const float*)d_in[0];
  const float* DWs    = (const float*)d_in[1];
  const float* sigmas = (const float*)d_in[2];
  const float* y_init = (const float*)d_in[3];
  const float* z_init = (const float*)d_in[4];
  const float* W1     = (const float*)d_in[5];
  const float* W2     = (const float*)d_in[6];
  const float* W3     = (const float*)d_in[7];
  const float* bn[16];
  for (int i = 0; i < 16; ++i) bn[i] = (const float*)d_in[8 + i];

  char* ws = (char*)d_ws;
  ushort_t* wprep = (ushort_t*)ws;                     // 87*14336*2 = 2,494,464 B
  float*    bprep = (float*)(ws + 2494464);            // 87*128*4   =    44,544 B
  float*    sbuf  = (float*)(ws + 2539008);            // 30*8192*4  =   983,040 B
  float*    out   = (float*)d_out;

  prep_kernel<<<dim3(3, TT), 256, 0, stream>>>(
      W1, W2, W3,
      bn[0], bn[1], bn[2], bn[3],  bn[4], bn[5], bn[6], bn[7],
      bn[8], bn[9], bn[10], bn[11], bn[12], bn[13], bn[14], bn[15],
      wprep, bprep);
  subnet_kernel<<<dim3(B_PATHS/64, TT), 256, 0, stream>>>(
      X, DWs, sigmas, wprep, bprep, sbuf);
  y_kernel<<<dim3(B_PATHS/256), 256, 0, stream>>>(
      X, DWs, sigmas, y_init, z_init, sbuf, out);
}